// Round 17
// baseline (571.779 us; speedup 1.0000x reference)
//
#include <hip/hip_runtime.h>

typedef _Float16 f16;
typedef _Float16 f16x2 __attribute__((ext_vector_type(2)));
typedef _Float16 f16x4 __attribute__((ext_vector_type(4)));
typedef _Float16 f16x8 __attribute__((ext_vector_type(8)));
typedef float    f32x4 __attribute__((ext_vector_type(4)));
typedef float    f32x16 __attribute__((ext_vector_type(16)));

#define SEQ 4096
#define HID 1024
#define NHEAD 16

__device__ __forceinline__ void gload_lds16(const void* src, void* dst) {
  __builtin_amdgcn_global_load_lds(
      (__attribute__((address_space(1))) void*)(void*)src,
      (__attribute__((address_space(3))) void*)dst, 16, 0, 0);
}

__device__ __forceinline__ float fast_exp2(float x) {
#if __has_builtin(__builtin_amdgcn_exp2f)
  return __builtin_amdgcn_exp2f(x);
#else
  float r;
  asm("v_exp_f32 %0, %1" : "=v"(r) : "v"(x));
  return r;
#endif
}

__device__ __forceinline__ f16x2 cvt_pk_f16(float a, float b) {
  return __builtin_bit_cast(f16x2, __builtin_amdgcn_cvt_pkrtz(a, b));
}

__device__ __forceinline__ void perm32swap(unsigned& a, unsigned& b) {
  asm volatile("v_permlane32_swap_b32 %0, %1" : "+v"(a), "+v"(b));
}

union U32F16x2 { unsigned u; f16x2 h; };
union PFU { unsigned u[4]; f16x8 v; };

// period-16 LDS column swizzle (2-way residual = free per m136)
#define SWZ(row) ((((row) & 7) ^ (((row) & 8) >> 1)))

// ---------------- conversions (x + all 4 weights, one launch) ----------------
__global__ void cvt_all(const float* __restrict__ x,
                        const float* __restrict__ Wq, const float* __restrict__ Wk,
                        const float* __restrict__ Wv, const float* __restrict__ Wo,
                        f16* __restrict__ x_h, f16* __restrict__ Wqkv,
                        f16* __restrict__ Wo_h) {
  int bx = blockIdx.x;
  const float* s;
  f16* o;
  long i;
  if (bx < 4096) {
    s = x; o = x_h;
    i = (long)bx * 256 + threadIdx.x;
  } else {
    int wsel = (bx - 4096) >> 10;
    i = (long)((bx - 4096) & 1023) * 256 + threadIdx.x;
    s = wsel == 0 ? Wq : wsel == 1 ? Wk : wsel == 2 ? Wv : Wo;
    o = wsel < 3 ? Wqkv + (long)wsel * HID * HID : Wo_h;
  }
  float4 v = ((const float4*)s)[i];
  f16x4 h;
  h[0] = (f16)v.x; h[1] = (f16)v.y; h[2] = (f16)v.z; h[3] = (f16)v.w;
  *(f16x4*)(o + i * 4) = h;
}

// sincos table for RoPE (shared across the 16 heads) + bias pack, one launch
__global__ void rope_tab_bias(const float* __restrict__ bq, const float* __restrict__ bk,
                              const float* __restrict__ bv, float* __restrict__ bqkv,
                              float2* __restrict__ tab) {
  int bx = blockIdx.x;
  if (bx < 512) {
    int idx = bx * 256 + threadIdx.x;  // [0, SEQ*32)
    int s = idx >> 5, j = idx & 31;
    float freq = __expf(-(float)j * 0.2878231366242557f);  // 10000^(-j/32)
    float sn, cs;
    sincosf((float)s * freq, &sn, &cs);
    tab[idx] = make_float2(cs, sn);
  } else {
    int i = (bx - 512) * 256 + threadIdx.x;
    if (i < 3 * HID) {
      float v = (i < HID) ? bq[i] : (i < 2 * HID ? bk[i - HID] : bv[i - 2 * HID]);
      bqkv[i] = v;
    }
  }
}

// ---------------- GEMM: C = A @ B^T (+bias [+resid]) ----------------
// MODE 0: QKV projection, plain bias epilogue. V cols stored to out2 in blocked
//         layout [head][kvblk=S/64][d64][kv64].
// MODE 1: out proj, float out = acc + bias + resid.
template <int MODE>
__global__ __launch_bounds__(256) void gemm_f16(
    const f16* __restrict__ A, const f16* __restrict__ B,
    const float* __restrict__ bias, const float* __restrict__ resid,
    void* __restrict__ out, void* __restrict__ out2,
    int M, int N, int K, int ldo) {
  __shared__ alignas(16) f16 As[128 * 64];
  __shared__ alignas(16) f16 Bs[128 * 64];
  const int tid = threadIdx.x;
  const int lane = tid & 63;
  const int w = tid >> 6;
  const int wr = w >> 1, wc = w & 1;
  const int l15 = lane & 15, g = lane >> 4;
  // XCD-aware bijective swizzle (nwg % 8 == 0 for both call sites)
  const int nwg = gridDim.x * gridDim.y;
  const int flat = blockIdx.y * gridDim.x + blockIdx.x;
  const int swz = (flat & 7) * (nwg >> 3) + (flat >> 3);
  const int m0 = (swz / gridDim.x) * 128;
  const int n0 = (swz % gridDim.x) * 128;

  f32x4 acc[4][4] = {};
  const int nkt = K >> 6;
  for (int kt = 0; kt < nkt; ++kt) {
#pragma unroll
    for (int i = 0; i < 4; ++i) {
      int c = i * 256 + w * 64 + lane;
      int row = c >> 3, c8 = c & 7;
      int so = ((c8 * 8) ^ ((row & 7) << 3)) + kt * 64;
      gload_lds16(A + (long)(m0 + row) * K + so, As + (i * 256 + w * 64) * 8);
      gload_lds16(B + (long)(n0 + row) * K + so, Bs + (i * 256 + w * 64) * 8);
    }
    __syncthreads();
#pragma unroll
    for (int kk = 0; kk < 2; ++kk) {
      f16x8 af[4], bf[4];
#pragma unroll
      for (int t = 0; t < 4; ++t) {
        int ra = wr * 64 + t * 16 + l15;
        af[t] = *(const f16x8*)(As + ra * 64 + ((kk * 32 + g * 8) ^ ((ra & 7) << 3)));
        int rb = wc * 64 + t * 16 + l15;
        bf[t] = *(const f16x8*)(Bs + rb * 64 + ((kk * 32 + g * 8) ^ ((rb & 7) << 3)));
      }
      __builtin_amdgcn_s_setprio(1);
#pragma unroll
      for (int mi = 0; mi < 4; ++mi)
#pragma unroll
        for (int ni = 0; ni < 4; ++ni)
          acc[mi][ni] = __builtin_amdgcn_mfma_f32_16x16x32_f16(af[mi], bf[ni], acc[mi][ni], 0, 0, 0);
      __builtin_amdgcn_s_setprio(0);
    }
    __syncthreads();
  }
#pragma unroll
  for (int mi = 0; mi < 4; ++mi) {
    int row = m0 + wr * 64 + mi * 16 + g * 4;
#pragma unroll
    for (int ni = 0; ni < 4; ++ni) {
      int col = n0 + wc * 64 + ni * 16 + l15;
      float bv = bias[col];
      if (MODE == 0) {
        if (col < 2 * HID) {
          f16* o = (f16*)out;
#pragma unroll
          for (int r = 0; r < 4; ++r)
            o[(long)(row + r) * ldo + col] = (f16)(acc[mi][ni][r] + bv);
        } else {
          // V block: blocked-transposed store [head][kvblk][d64][kv64]
          f16* vtp = (f16*)out2;
          f16x4 pk;
#pragma unroll
          for (int r = 0; r < 4; ++r) pk[r] = (f16)(acc[mi][ni][r] + bv);
          int cv = col - 2 * HID;          // 0..1023
          int headv = cv >> 6, dv = cv & 63;
          *(f16x4*)(vtp + (long)headv * SEQ * 64 + (long)(row >> 6) * 4096 +
                    dv * 64 + (row & 63)) = pk;
        }
      } else {
        float* o = (float*)out;
#pragma unroll
        for (int r = 0; r < 4; ++r)
          o[(long)(row + r) * ldo + col] =
              acc[mi][ni][r] + bv + resid[(long)(row + r) * HID + col];
      }
    }
  }
}

// ---------------- RoPE in place on Q and K halves of qkv (table-driven) --------
// Q additionally pre-scaled by 0.125*log2(e) (rotation and scale commute).
__global__ void rope_kernel(f16* __restrict__ qkv, const float2* __restrict__ tab) {
  int idx = blockIdx.x * 256 + threadIdx.x;  // [0, SEQ*16*4)
  int u = idx & 3, h = (idx >> 2) & 15, s = idx >> 6;
  const float2* tp = tab + s * 32 + u * 8;
  const float qsc = 0.18033688f;
  f16* qp = qkv + (long)s * 3072 + h * 64 + u * 8;
  f16x8 qlo = *(const f16x8*)qp;
  f16x8 qhi = *(const f16x8*)(qp + 32);
  f16x8 klo = *(const f16x8*)(qp + HID);
  f16x8 khi = *(const f16x8*)(qp + HID + 32);
  f16x8 nql, nqh, nkl, nkh;
#pragma unroll
  for (int i = 0; i < 8; ++i) {
    float cs = tp[i].x, sn = tp[i].y;
    nql[i] = (f16)(((float)qlo[i] * cs - (float)qhi[i] * sn) * qsc);
    nqh[i] = (f16)(((float)qhi[i] * cs + (float)qlo[i] * sn) * qsc);
    nkl[i] = (f16)((float)klo[i] * cs - (float)khi[i] * sn);
    nkh[i] = (f16)((float)khi[i] * cs + (float)klo[i] * sn);
  }
  *(f16x8*)qp = nql;
  *(f16x8*)(qp + 32) = nqh;
  *(f16x8*)(qp + HID) = nkl;
  *(f16x8*)(qp + HID + 32) = nkh;
}

// ---------------- flash attention (swapped 32x32, no-max softmax, KV-split NS) ----
// 8-wave blocks (512 thr) sharing one K/V LDS tile: 4 blocks/CU x 8 waves =
// 32 waves/CU = 100% occupancy (vs 50% at 4-wave blocks). XCD-clustered;
// V blocked [head][kvblk][d64][kv64]; row-sum via ones-MFMA.
// grid (16, 16, NS); wave owns 32 q rows (q = lane&31).
// Q arrives pre-scaled by 0.125*log2(e) (folded into rope).
template <int NS>
__global__ __launch_bounds__(512, 8) void flash_attn(
    const f16* __restrict__ qkv, const f16* __restrict__ vt,
    f16* __restrict__ ctx_or_part, float* __restrict__ gbuf) {
  __shared__ alignas(16) f16 SM[4][64 * 64];  // [K0, K1, V0, V1]
  const int tid = threadIdx.x, lane = tid & 63, w = tid >> 6;  // w in [0,8)
  const int l31 = lane & 31, hi = lane >> 5;
  // XCD remap: hw xcd = flat%8; group g=(head,z) constant per XCD.
  // flat = bx + by*16 + bz*256; g = (flat&7) + 8*(flat>>7); seq = (flat>>3)&15.
  const int flat = blockIdx.x + ((blockIdx.y + (blockIdx.z << 4)) << 4);
  const int seq_all = flat >> 3;
  const int g = (flat & 7) + ((seq_all >> 4) << 3);
  const int head = g & 15;
  const int z = (NS > 1) ? (g >> 4) : 0;
  const int q0 = (seq_all & 15) * 256 + w * 32;
  const int span = SEQ / NS;
  const int kvbase = z * span;

  // Q fragments: q-row = l31, d = dt*16 + hi*8 + i (already scaled).
  f16x8 qf[4];
  {
    const f16* qp = qkv + (long)(q0 + l31) * 3072 + head * 64 + hi * 8;
#pragma unroll
    for (int dt = 0; dt < 4; ++dt)
      qf[dt] = *(const f16x8*)(qp + dt * 16);
  }
  f16x8 ones;
#pragma unroll
  for (int i = 0; i < 8; ++i) ones[i] = (f16)1.0f;

  const f16* kbase = qkv + HID + head * 64;
  const f16* vbase = vt + (long)head * SEQ * 64;

  f32x16 oacc[2] = {};  // O^T[d][q=l31]; d = dsub*32 + (r&3)+8*(r>>2)+4*hi
  f32x16 lacc = {};     // ones-MFMA row-sum; every element = sum_kv P[kv][q]

  // 512 threads: each thread stages one 16B chunk of K and one of V per tile.
#define STAGE(buf, kv0)                                                            \
  {                                                                                \
    int c = tid;                                                                   \
    int row = c >> 3, c8 = c & 7;                                                  \
    int so = (c8 ^ SWZ(row)) * 8;                                                  \
    gload_lds16(kbase + (long)((kv0) + row) * 3072 + so, &SM[buf][c * 8]);         \
    gload_lds16(vbase + (long)((kv0) >> 6) * 4096 + row * 64 + so,                 \
                &SM[2 + (buf)][c * 8]);                                            \
  }

  STAGE(0, kvbase);
  __syncthreads();

  for (int it = 0; it < span / 64; ++it) {
    const int cur = it & 1;
    if (it + 1 < span / 64) STAGE(cur ^ 1, kvbase + it * 64 + 64);

    // S^T[kv][q] = K · Q^T  (dt-major: the two sacc chains interleave, dep dist 2)
    f32x16 sacc[2] = {};
    __builtin_amdgcn_s_setprio(1);
#pragma unroll
    for (int dt = 0; dt < 4; ++dt) {
#pragma unroll
      for (int sub = 0; sub < 2; ++sub) {
        int row = sub * 32 + l31;
        f16x8 kf = *(const f16x8*)(&SM[cur][row * 64 +
                                            ((dt * 16 + hi * 8) ^ (SWZ(row) << 3))]);
        sacc[sub] = __builtin_amdgcn_mfma_f32_32x32x16_f16(kf, qf[dt], sacc[sub], 0, 0, 0);
      }
    }
    __builtin_amdgcn_s_setprio(0);

    // ---- softmax numerator, no max-shift: P = exp2(s) directly ----
    f16x2 h[16];
#pragma unroll
    for (int sub = 0; sub < 2; ++sub)
#pragma unroll
      for (int u = 0; u < 8; ++u) {
        float p0 = fast_exp2(sacc[sub][2 * u]);
        float p1 = fast_exp2(sacc[sub][2 * u + 1]);
        h[sub * 8 + u] = cvt_pk_f16(p0, p1);
      }

    // T12: permlane32_swap so P fragment kv-map becomes kv = t*16 + 8*hi + j
    f16x8 pf[4];
#pragma unroll
    for (int t = 0; t < 4; ++t) {
      int base = (t >> 1) * 8 + (t & 1) * 4;
      U32F16x2 c0, c1, c2, c3;
      c0.h = h[base + 0]; c1.h = h[base + 1];
      c2.h = h[base + 2]; c3.h = h[base + 3];
      perm32swap(c0.u, c2.u);
      perm32swap(c1.u, c3.u);
      PFU p;
      p.u[0] = c0.u; p.u[1] = c1.u; p.u[2] = c2.u; p.u[3] = c3.u;
      pf[t] = p.v;
    }

    // O^T += V^T · P — contiguous b128 V reads (kv = t*16 + 8*hi + 0..7);
    // l += ones · P (row-sum on the MFMA pipe)
    __builtin_amdgcn_s_setprio(1);
#pragma unroll
    for (int dsub = 0; dsub < 2; ++dsub) {
      int row = dsub * 32 + l31;
      const f16* vrow = &SM[2 + cur][row * 64];
      int sw = SWZ(row) << 3;
#pragma unroll
      for (int t = 0; t < 4; ++t) {
        f16x8 af = *(const f16x8*)(vrow + ((t * 16 + hi * 8) ^ sw));
        oacc[dsub] = __builtin_amdgcn_mfma_f32_32x32x16_f16(af, pf[t], oacc[dsub], 0, 0, 0);
      }
    }
#pragma unroll
    for (int t = 0; t < 4; ++t)
      lacc = __builtin_amdgcn_mfma_f32_32x32x16_f16(ones, pf[t], lacc, 0, 0, 0);
    __builtin_amdgcn_s_setprio(0);
    __syncthreads();
  }

  // epilogue: l = lacc[0]; normalize, transpose O^T -> O via LDS
  // (rotation swizzle: halfs offset (d + 2*row) & 63 -> conflict-free).
  // 8 waves x 2048 halfs = the whole 32KB SM arena.
  float l_r = lacc[0];
  f16* ob = &SM[0][0] + w * 2048;  // wave-local 32x64 tile
  float linv = 1.0f / l_r;
#pragma unroll
  for (int dsub = 0; dsub < 2; ++dsub)
#pragma unroll
    for (int a = 0; a < 8; ++a) {
      int rr = a * 2;
      int d = dsub * 32 + (rr & 3) + 8 * (rr >> 2) + 4 * hi;  // d, d+1 pair
      f16x2 pk;
      pk[0] = (f16)(oacc[dsub][rr] * linv);
      pk[1] = (f16)(oacc[dsub][rr + 1] * linv);
      *(f16x2*)(ob + l31 * 64 + ((d + 2 * l31) & 63)) = pk;
    }
  if (NS > 1 && hi == 0)
    gbuf[(long)z * SEQ * NHEAD + (long)(q0 + l31) * NHEAD + head] = __log2f(l_r);
  {
    f16* obase = (NS > 1) ? ctx_or_part + (long)z * SEQ * HID : ctx_or_part;
    int dblk = lane & 7, r0 = lane >> 3;
#pragma unroll
    for (int j = 0; j < 4; ++j) {
      int q = r0 + j * 8;
      f16x2 vv[4];
#pragma unroll
      for (int i = 0; i < 4; ++i)
        vv[i] = *(const f16x2*)(ob + q * 64 + ((dblk * 8 + 2 * i + 2 * q) & 63));
      f16x8 o8;
#pragma unroll
      for (int i = 0; i < 4; ++i) { o8[2 * i] = vv[i][0]; o8[2 * i + 1] = vv[i][1]; }
      *(f16x8*)(obase + (long)(q0 + q) * HID + head * 64 + dblk * 8) = o8;
    }
  }
#undef STAGE
}

// combine NS normalized partials: w_z = 2^(g_z - G) softmax weights
template <int NS>
__global__ __launch_bounds__(256) void combine_kernel(
    const f16* __restrict__ part, const float* __restrict__ g,
    f16* __restrict__ ctx) {
  long idx = (long)blockIdx.x * 256 + threadIdx.x;  // [0, SEQ*128)
  int q = (int)(idx >> 7), c = (int)(idx & 127);
  int head = c >> 3;
  float gv[NS];
  float G = -1e30f;
#pragma unroll
  for (int zz = 0; zz < NS; ++zz) {
    gv[zz] = g[(long)zz * SEQ * NHEAD + (long)q * NHEAD + head];
    G = fmaxf(G, gv[zz]);
  }
  float wz[NS], tot = 0.f;
#pragma unroll
  for (int zz = 0; zz < NS; ++zz) { wz[zz] = fast_exp2(gv[zz] - G); tot += wz[zz]; }
  float inv = 1.f / tot;
  float acc[8] = {};
#pragma unroll
  for (int zz = 0; zz < NS; ++zz) {
    f16x8 a = *(const f16x8*)(part + (long)zz * SEQ * HID + (long)q * HID + c * 8);
    float wzz = wz[zz] * inv;
#pragma unroll
    for (int j = 0; j < 8; ++j) acc[j] += (float)a[j] * wzz;
  }
  f16x8 o;
#pragma unroll
  for (int j = 0; j < 8; ++j) o[j] = (f16)acc[j];
  *(f16x8*)(ctx + (long)q * HID + c * 8) = o;
}

// ---------------- LayerNorm ----------------
__global__ __launch_bounds__(256) void ln_kernel(
    const float* __restrict__ res, const float* __restrict__ gamma,
    const float* __restrict__ beta, float* __restrict__ out) {
  int row = blockIdx.x;
  int t = threadIdx.x;
  float4 v = ((const float4*)(res + (long)row * HID))[t];
  float s = v.x + v.y + v.z + v.w;
  float s2 = v.x * v.x + v.y * v.y + v.z * v.z + v.w * v.w;
#pragma unroll
  for (int off = 1; off < 64; off <<= 1) {
    s += __shfl_xor(s, off);
    s2 += __shfl_xor(s2, off);
  }
  __shared__ float sm[8];
  int w = t >> 6, lane = t & 63;
  if (lane == 0) { sm[w] = s; sm[4 + w] = s2; }
  __syncthreads();
  s = sm[0] + sm[1] + sm[2] + sm[3];
  s2 = sm[4] + sm[5] + sm[6] + sm[7];
  float mean = s * (1.f / HID);
  float var = s2 * (1.f / HID) - mean * mean;
  float rstd = rsqrtf(var + 1e-5f);
  float4 g4 = ((const float4*)gamma)[t];
  float4 b4 = ((const float4*)beta)[t];
  float4 ov;
  ov.x = (v.x - mean) * rstd * g4.x + b4.x;
  ov.y = (v.y - mean) * rstd * g4.y + b4.y;
  ov.z = (v.z - mean) * rstd * g4.z + b4.z;
  ov.w = (v.w - mean) * rstd * g4.w + b4.w;
  ((float4*)(out + (long)row * HID))[t] = ov;
}

extern "C" void kernel_launch(void* const* d_in, const int* in_sizes, int n_in,
                              void* d_out, int out_size, void* d_ws, size_t ws_size,
                              hipStream_t stream) {
  const float* x = (const float*)d_in[0];
  const float* Wq = (const float*)d_in[1];
  const float* bq = (const float*)d_in[2];
  const float* Wk = (const float*)d_in[3];
  const float* bk = (const float*)d_in[4];
  const float* Wv = (const float*)d_in[5];
  const float* bv = (const float*)d_in[6];
  const float* Wo = (const float*)d_in[7];
  const float* bo = (const float*)d_in[8];
  const float* gamma = (const float*)d_in[9];
  const float* beta = (const float*)d_in[10];

  char* ws = (char*)d_ws;
  f16* x_h = (f16*)(ws);                       //  8 MB (dead after QKV gemm)
  f16* Wqkv = (f16*)(ws + (8ll << 20));        //  6 MB
  f16* Wo_h = (f16*)(ws + (14ll << 20));       //  2 MB
  float* bqkv = (float*)(ws + (16ll << 20));   // 12 KB
  f16* qkv = (f16*)(ws + (17ll << 20));        // 24 MB [S,3072]
  f16* vt = (f16*)(ws + (41ll << 20));         //  8 MB blocked [16][64][64][64]
  f16* ctx = (f16*)(ws + (49ll << 20));        //  8 MB
  f16* part = (f16*)(ws + (57ll << 20));       // 32 MB [4][S][HID] (dead after combine)
  float* gbuf = (float*)(ws + (89ll << 20));   //  1 MB [4][S][NHEAD]
  float* res = (float*)(ws + (57ll << 20));    // 16 MB (overlays part[0..1], after combine)
  float2* tab = (float2*)(ws + (88ll << 20));  //  1 MB sincos (overlays part[3]; dead
                                               //  after rope, before attn writes part)
  const bool split = ws_size >= (90ull << 20);

  cvt_all<<<8192, 256, 0, stream>>>(x, Wq, Wk, Wv, Wo, x_h, Wqkv, Wo_h);
  rope_tab_bias<<<524, 256, 0, stream>>>(bq, bk, bv, bqkv, tab);

  gemm_f16<0><<<dim3(24, 32), 256, 0, stream>>>(x_h, Wqkv, bqkv, nullptr,
                                                qkv, vt, SEQ, 3 * HID, HID, 3 * HID);
  rope_kernel<<<SEQ * NHEAD * 4 / 256, 256, 0, stream>>>(qkv, tab);
  if (split) {
    flash_attn<4><<<dim3(SEQ / 256, NHEAD, 4), 512, 0, stream>>>(qkv, vt, part, gbuf);
    combine_kernel<4><<<SEQ * 128 / 256, 256, 0, stream>>>(part, gbuf, ctx);
  } else {
    flash_attn<1><<<dim3(SEQ / 256, NHEAD, 1), 512, 0, stream>>>(qkv, vt, ctx, nullptr);
  }
  gemm_f16<1><<<dim3(8, 32), 256, 0, stream>>>(ctx, Wo_h, bo, x,
                                               res, nullptr, SEQ, HID, HID, HID);
  ln_kernel<<<SEQ, 256, 0, stream>>>(res, gamma, beta, (float*)d_out);
}

// Round 18
// 175.470 us; speedup vs baseline: 3.2585x; 3.2585x over previous
//
#include <hip/hip_runtime.h>

typedef _Float16 f16;
typedef _Float16 f16x2 __attribute__((ext_vector_type(2)));
typedef _Float16 f16x4 __attribute__((ext_vector_type(4)));
typedef _Float16 f16x8 __attribute__((ext_vector_type(8)));
typedef float    f32x4 __attribute__((ext_vector_type(4)));
typedef float    f32x16 __attribute__((ext_vector_type(16)));

#define SEQ 4096
#define HID 1024
#define NHEAD 16

__device__ __forceinline__ void gload_lds16(const void* src, void* dst) {
  __builtin_amdgcn_global_load_lds(
      (__attribute__((address_space(1))) void*)(void*)src,
      (__attribute__((address_space(3))) void*)dst, 16, 0, 0);
}

__device__ __forceinline__ float fast_exp2(float x) {
#if __has_builtin(__builtin_amdgcn_exp2f)
  return __builtin_amdgcn_exp2f(x);
#else
  float r;
  asm("v_exp_f32 %0, %1" : "=v"(r) : "v"(x));
  return r;
#endif
}

__device__ __forceinline__ f16x2 cvt_pk_f16(float a, float b) {
  return __builtin_bit_cast(f16x2, __builtin_amdgcn_cvt_pkrtz(a, b));
}

__device__ __forceinline__ void perm32swap(unsigned& a, unsigned& b) {
  asm volatile("v_permlane32_swap_b32 %0, %1" : "+v"(a), "+v"(b));
}

union U32F16x2 { unsigned u; f16x2 h; };
union PFU { unsigned u[4]; f16x8 v; };

// period-16 LDS column swizzle (2-way residual = free per m136)
#define SWZ(row) ((((row) & 7) ^ (((row) & 8) >> 1)))

// ---------------- conversions (x + all 4 weights, one launch) ----------------
__global__ void cvt_all(const float* __restrict__ x,
                        const float* __restrict__ Wq, const float* __restrict__ Wk,
                        const float* __restrict__ Wv, const float* __restrict__ Wo,
                        f16* __restrict__ x_h, f16* __restrict__ Wqkv,
                        f16* __restrict__ Wo_h) {
  int bx = blockIdx.x;
  const float* s;
  f16* o;
  long i;
  if (bx < 4096) {
    s = x; o = x_h;
    i = (long)bx * 256 + threadIdx.x;
  } else {
    int wsel = (bx - 4096) >> 10;
    i = (long)((bx - 4096) & 1023) * 256 + threadIdx.x;
    s = wsel == 0 ? Wq : wsel == 1 ? Wk : wsel == 2 ? Wv : Wo;
    o = wsel < 3 ? Wqkv + (long)wsel * HID * HID : Wo_h;
  }
  float4 v = ((const float4*)s)[i];
  f16x4 h;
  h[0] = (f16)v.x; h[1] = (f16)v.y; h[2] = (f16)v.z; h[3] = (f16)v.w;
  *(f16x4*)(o + i * 4) = h;
}

// sincos table for RoPE (shared across the 16 heads) + bias pack, one launch
__global__ void rope_tab_bias(const float* __restrict__ bq, const float* __restrict__ bk,
                              const float* __restrict__ bv, float* __restrict__ bqkv,
                              float2* __restrict__ tab) {
  int bx = blockIdx.x;
  if (bx < 512) {
    int idx = bx * 256 + threadIdx.x;  // [0, SEQ*32)
    int s = idx >> 5, j = idx & 31;
    float freq = __expf(-(float)j * 0.2878231366242557f);  // 10000^(-j/32)
    float sn, cs;
    sincosf((float)s * freq, &sn, &cs);
    tab[idx] = make_float2(cs, sn);
  } else {
    int i = (bx - 512) * 256 + threadIdx.x;
    if (i < 3 * HID) {
      float v = (i < HID) ? bq[i] : (i < 2 * HID ? bk[i - HID] : bv[i - 2 * HID]);
      bqkv[i] = v;
    }
  }
}

// ---------------- GEMM: C = A @ B^T (+bias [+resid]) ----------------
// MODE 0: QKV projection, plain bias epilogue. V cols stored to out2 in blocked
//         layout [head][kvblk=S/64][d64][kv64].
// MODE 1: out proj, float out = acc + bias + resid.
template <int MODE>
__global__ __launch_bounds__(256) void gemm_f16(
    const f16* __restrict__ A, const f16* __restrict__ B,
    const float* __restrict__ bias, const float* __restrict__ resid,
    void* __restrict__ out, void* __restrict__ out2,
    int M, int N, int K, int ldo) {
  __shared__ alignas(16) f16 As[128 * 64];
  __shared__ alignas(16) f16 Bs[128 * 64];
  const int tid = threadIdx.x;
  const int lane = tid & 63;
  const int w = tid >> 6;
  const int wr = w >> 1, wc = w & 1;
  const int l15 = lane & 15, g = lane >> 4;
  // XCD-aware bijective swizzle (nwg % 8 == 0 for both call sites)
  const int nwg = gridDim.x * gridDim.y;
  const int flat = blockIdx.y * gridDim.x + blockIdx.x;
  const int swz = (flat & 7) * (nwg >> 3) + (flat >> 3);
  const int m0 = (swz / gridDim.x) * 128;
  const int n0 = (swz % gridDim.x) * 128;

  f32x4 acc[4][4] = {};
  const int nkt = K >> 6;
  for (int kt = 0; kt < nkt; ++kt) {
#pragma unroll
    for (int i = 0; i < 4; ++i) {
      int c = i * 256 + w * 64 + lane;
      int row = c >> 3, c8 = c & 7;
      int so = ((c8 * 8) ^ ((row & 7) << 3)) + kt * 64;
      gload_lds16(A + (long)(m0 + row) * K + so, As + (i * 256 + w * 64) * 8);
      gload_lds16(B + (long)(n0 + row) * K + so, Bs + (i * 256 + w * 64) * 8);
    }
    __syncthreads();
#pragma unroll
    for (int kk = 0; kk < 2; ++kk) {
      f16x8 af[4], bf[4];
#pragma unroll
      for (int t = 0; t < 4; ++t) {
        int ra = wr * 64 + t * 16 + l15;
        af[t] = *(const f16x8*)(As + ra * 64 + ((kk * 32 + g * 8) ^ ((ra & 7) << 3)));
        int rb = wc * 64 + t * 16 + l15;
        bf[t] = *(const f16x8*)(Bs + rb * 64 + ((kk * 32 + g * 8) ^ ((rb & 7) << 3)));
      }
      __builtin_amdgcn_s_setprio(1);
#pragma unroll
      for (int mi = 0; mi < 4; ++mi)
#pragma unroll
        for (int ni = 0; ni < 4; ++ni)
          acc[mi][ni] = __builtin_amdgcn_mfma_f32_16x16x32_f16(af[mi], bf[ni], acc[mi][ni], 0, 0, 0);
      __builtin_amdgcn_s_setprio(0);
    }
    __syncthreads();
  }
#pragma unroll
  for (int mi = 0; mi < 4; ++mi) {
    int row = m0 + wr * 64 + mi * 16 + g * 4;
#pragma unroll
    for (int ni = 0; ni < 4; ++ni) {
      int col = n0 + wc * 64 + ni * 16 + l15;
      float bv = bias[col];
      if (MODE == 0) {
        if (col < 2 * HID) {
          f16* o = (f16*)out;
#pragma unroll
          for (int r = 0; r < 4; ++r)
            o[(long)(row + r) * ldo + col] = (f16)(acc[mi][ni][r] + bv);
        } else {
          // V block: blocked-transposed store [head][kvblk][d64][kv64]
          f16* vtp = (f16*)out2;
          f16x4 pk;
#pragma unroll
          for (int r = 0; r < 4; ++r) pk[r] = (f16)(acc[mi][ni][r] + bv);
          int cv = col - 2 * HID;          // 0..1023
          int headv = cv >> 6, dv = cv & 63;
          *(f16x4*)(vtp + (long)headv * SEQ * 64 + (long)(row >> 6) * 4096 +
                    dv * 64 + (row & 63)) = pk;
        }
      } else {
        float* o = (float*)out;
#pragma unroll
        for (int r = 0; r < 4; ++r)
          o[(long)(row + r) * ldo + col] =
              acc[mi][ni][r] + bv + resid[(long)(row + r) * HID + col];
      }
    }
  }
}

// ---------------- RoPE in place on Q and K halves of qkv (table-driven) --------
// Q additionally pre-scaled by 0.125*log2(e) (rotation and scale commute).
__global__ void rope_kernel(f16* __restrict__ qkv, const float2* __restrict__ tab) {
  int idx = blockIdx.x * 256 + threadIdx.x;  // [0, SEQ*16*4)
  int u = idx & 3, h = (idx >> 2) & 15, s = idx >> 6;
  const float2* tp = tab + s * 32 + u * 8;
  const float qsc = 0.18033688f;
  f16* qp = qkv + (long)s * 3072 + h * 64 + u * 8;
  f16x8 qlo = *(const f16x8*)qp;
  f16x8 qhi = *(const f16x8*)(qp + 32);
  f16x8 klo = *(const f16x8*)(qp + HID);
  f16x8 khi = *(const f16x8*)(qp + HID + 32);
  f16x8 nql, nqh, nkl, nkh;
#pragma unroll
  for (int i = 0; i < 8; ++i) {
    float cs = tp[i].x, sn = tp[i].y;
    nql[i] = (f16)(((float)qlo[i] * cs - (float)qhi[i] * sn) * qsc);
    nqh[i] = (f16)(((float)qhi[i] * cs + (float)qlo[i] * sn) * qsc);
    nkl[i] = (f16)((float)klo[i] * cs - (float)khi[i] * sn);
    nkh[i] = (f16)((float)khi[i] * cs + (float)klo[i] * sn);
  }
  *(f16x8*)qp = nql;
  *(f16x8*)(qp + 32) = nqh;
  *(f16x8*)(qp + HID) = nkl;
  *(f16x8*)(qp + HID + 32) = nkh;
}

// ---------------- flash attention (swapped 32x32, no-max softmax, KV-split NS) ----
// XCD-clustered; V blocked [head][kvblk][d64][kv64]; f32-sum softmax (R13-best).
// grid (32, 16, NS), 256 threads = 4 waves; wave owns 32 q rows (q=lane&31).
// Q arrives pre-scaled by 0.125*log2(e) (folded into rope).
// launch_bounds(256,4) — unified VGPR+AGPR file caps this state at 4 waves/SIMD;
// (256,5)/(512,8) both force spill storms (R14/R17).
template <int NS>
__global__ __launch_bounds__(256, 4) void flash_attn(
    const f16* __restrict__ qkv, const f16* __restrict__ vt,
    f16* __restrict__ ctx_or_part, float* __restrict__ gbuf) {
  __shared__ alignas(16) f16 Ks[2][64 * 64];
  __shared__ alignas(16) f16 Vs[2][64 * 64];  // [d][kv]
  const int tid = threadIdx.x, lane = tid & 63, w = tid >> 6;
  const int l31 = lane & 31, hi = lane >> 5;
  // XCD remap: hw xcd = flat%8; group g=(head,z) constant per XCD
  const int flat = blockIdx.x + ((blockIdx.y + (blockIdx.z << 4)) << 5);
  const int seq = flat >> 3;
  const int g = (flat & 7) + ((seq >> 5) << 3);
  const int head = g & 15;
  const int z = (NS > 1) ? (g >> 4) : 0;
  const int q0 = (seq & 31) * 128 + w * 32;
  const int span = SEQ / NS;
  const int kvbase = z * span;

  // Q fragments: q-row = l31, d = dt*16 + hi*8 + i (already scaled).
  f16x8 qf[4];
  {
    const f16* qp = qkv + (long)(q0 + l31) * 3072 + head * 64 + hi * 8;
#pragma unroll
    for (int dt = 0; dt < 4; ++dt)
      qf[dt] = *(const f16x8*)(qp + dt * 16);
  }

  const f16* kbase = qkv + HID + head * 64;
  const f16* vbase = vt + (long)head * SEQ * 64;

  float l_r = 0.f;
  f32x16 oacc[2] = {};  // O^T[d][q=l31]; d = dsub*32 + (r&3)+8*(r>>2)+4*hi

#define STAGE(buf, kv0)                                                            \
  {                                                                                \
    _Pragma("unroll") for (int i = 0; i < 2; ++i) {                                \
      int c = i * 256 + w * 64 + lane;                                             \
      int row = c >> 3, c8 = c & 7;                                                \
      int so = (c8 ^ SWZ(row)) * 8;                                                \
      gload_lds16(kbase + (long)((kv0) + row) * 3072 + so,                         \
                  &Ks[buf][(i * 256 + w * 64) * 8]);                               \
      gload_lds16(vbase + (long)((kv0) >> 6) * 4096 + row * 64 + so,               \
                  &Vs[buf][(i * 256 + w * 64) * 8]);                               \
    }                                                                              \
  }

  STAGE(0, kvbase);
  __syncthreads();

  for (int it = 0; it < span / 64; ++it) {
    const int cur = it & 1;
    if (it + 1 < span / 64) STAGE(cur ^ 1, kvbase + it * 64 + 64);

    // S^T[kv][q] = K · Q^T  (dt-major: the two sacc chains interleave, dep dist 2)
    f32x16 sacc[2] = {};
    __builtin_amdgcn_s_setprio(1);
#pragma unroll
    for (int dt = 0; dt < 4; ++dt) {
#pragma unroll
      for (int sub = 0; sub < 2; ++sub) {
        int row = sub * 32 + l31;
        f16x8 kf = *(const f16x8*)(&Ks[cur][row * 64 +
                                            ((dt * 16 + hi * 8) ^ (SWZ(row) << 3))]);
        sacc[sub] = __builtin_amdgcn_mfma_f32_32x32x16_f16(kf, qf[dt], sacc[sub], 0, 0, 0);
      }
    }
    __builtin_amdgcn_s_setprio(0);

    // ---- softmax numerator, no max-shift: P = exp2(s) directly ----
    f16x2 h[16];
    float sm0 = 0.f, sm1 = 0.f, sm2 = 0.f, sm3 = 0.f;
#pragma unroll
    for (int sub = 0; sub < 2; ++sub)
#pragma unroll
      for (int u = 0; u < 8; ++u) {
        float p0 = fast_exp2(sacc[sub][2 * u]);
        float p1 = fast_exp2(sacc[sub][2 * u + 1]);
        h[sub * 8 + u] = cvt_pk_f16(p0, p1);
        if (sub == 0) { sm0 += p0; sm1 += p1; }
        else          { sm2 += p0; sm3 += p1; }
      }
    float sum = (sm0 + sm1) + (sm2 + sm3);
    sum += __shfl_xor(sum, 32);
    l_r += sum;

    // T12: permlane32_swap so P fragment kv-map becomes kv = t*16 + 8*hi + j
    f16x8 pf[4];
#pragma unroll
    for (int t = 0; t < 4; ++t) {
      int base = (t >> 1) * 8 + (t & 1) * 4;
      U32F16x2 c0, c1, c2, c3;
      c0.h = h[base + 0]; c1.h = h[base + 1];
      c2.h = h[base + 2]; c3.h = h[base + 3];
      perm32swap(c0.u, c2.u);
      perm32swap(c1.u, c3.u);
      PFU p;
      p.u[0] = c0.u; p.u[1] = c1.u; p.u[2] = c2.u; p.u[3] = c3.u;
      pf[t] = p.v;
    }

    // O^T += V^T · P — contiguous b128 V reads (kv = t*16 + 8*hi + 0..7)
    __builtin_amdgcn_s_setprio(1);
#pragma unroll
    for (int dsub = 0; dsub < 2; ++dsub) {
      int row = dsub * 32 + l31;
      const f16* vrow = &Vs[cur][row * 64];
      int sw = SWZ(row) << 3;
#pragma unroll
      for (int t = 0; t < 4; ++t) {
        f16x8 af = *(const f16x8*)(vrow + ((t * 16 + hi * 8) ^ sw));
        oacc[dsub] = __builtin_amdgcn_mfma_f32_32x32x16_f16(af, pf[t], oacc[dsub], 0, 0, 0);
      }
    }
    __builtin_amdgcn_s_setprio(0);
    __syncthreads();
  }

  // epilogue: normalize, transpose O^T -> O via LDS (rotation swizzle, conflict-free)
  f16* ob = &Ks[0][0] + w * 2048;  // wave-local 32x64 tile
  float linv = 1.0f / l_r;
#pragma unroll
  for (int dsub = 0; dsub < 2; ++dsub)
#pragma unroll
    for (int a = 0; a < 8; ++a) {
      int rr = a * 2;
      int d = dsub * 32 + (rr & 3) + 8 * (rr >> 2) + 4 * hi;  // d, d+1 pair
      f16x2 pk;
      pk[0] = (f16)(oacc[dsub][rr] * linv);
      pk[1] = (f16)(oacc[dsub][rr + 1] * linv);
      *(f16x2*)(ob + l31 * 64 + ((d + 2 * l31) & 63)) = pk;
    }
  if (NS > 1 && hi == 0)
    gbuf[(long)z * SEQ * NHEAD + (long)(q0 + l31) * NHEAD + head] = __log2f(l_r);
  {
    f16* obase = (NS > 1) ? ctx_or_part + (long)z * SEQ * HID : ctx_or_part;
    int dblk = lane & 7, r0 = lane >> 3;
#pragma unroll
    for (int j = 0; j < 4; ++j) {
      int q = r0 + j * 8;
      f16x2 vv[4];
#pragma unroll
      for (int i = 0; i < 4; ++i)
        vv[i] = *(const f16x2*)(ob + q * 64 + ((dblk * 8 + 2 * i + 2 * q) & 63));
      f16x8 o8;
#pragma unroll
      for (int i = 0; i < 4; ++i) { o8[2 * i] = vv[i][0]; o8[2 * i + 1] = vv[i][1]; }
      *(f16x8*)(obase + (long)(q0 + q) * HID + head * 64 + dblk * 8) = o8;
    }
  }
#undef STAGE
}

// combine NS normalized partials: w_z = 2^(g_z - G) softmax weights
template <int NS>
__global__ __launch_bounds__(256) void combine_kernel(
    const f16* __restrict__ part, const float* __restrict__ g,
    f16* __restrict__ ctx) {
  long idx = (long)blockIdx.x * 256 + threadIdx.x;  // [0, SEQ*128)
  int q = (int)(idx >> 7), c = (int)(idx & 127);
  int head = c >> 3;
  float gv[NS];
  float G = -1e30f;
#pragma unroll
  for (int zz = 0; zz < NS; ++zz) {
    gv[zz] = g[(long)zz * SEQ * NHEAD + (long)q * NHEAD + head];
    G = fmaxf(G, gv[zz]);
  }
  float wz[NS], tot = 0.f;
#pragma unroll
  for (int zz = 0; zz < NS; ++zz) { wz[zz] = fast_exp2(gv[zz] - G); tot += wz[zz]; }
  float inv = 1.f / tot;
  float acc[8] = {};
#pragma unroll
  for (int zz = 0; zz < NS; ++zz) {
    f16x8 a = *(const f16x8*)(part + (long)zz * SEQ * HID + (long)q * HID + c * 8);
    float wzz = wz[zz] * inv;
#pragma unroll
    for (int j = 0; j < 8; ++j) acc[j] += (float)a[j] * wzz;
  }
  f16x8 o;
#pragma unroll
  for (int j = 0; j < 8; ++j) o[j] = (f16)acc[j];
  *(f16x8*)(ctx + (long)q * HID + c * 8) = o;
}

// ---------------- LayerNorm ----------------
__global__ __launch_bounds__(256) void ln_kernel(
    const float* __restrict__ res, const float* __restrict__ gamma,
    const float* __restrict__ beta, float* __restrict__ out) {
  int row = blockIdx.x;
  int t = threadIdx.x;
  float4 v = ((const float4*)(res + (long)row * HID))[t];
  float s = v.x + v.y + v.z + v.w;
  float s2 = v.x * v.x + v.y * v.y + v.z * v.z + v.w * v.w;
#pragma unroll
  for (int off = 1; off < 64; off <<= 1) {
    s += __shfl_xor(s, off);
    s2 += __shfl_xor(s2, off);
  }
  __shared__ float sm[8];
  int w = t >> 6, lane = t & 63;
  if (lane == 0) { sm[w] = s; sm[4 + w] = s2; }
  __syncthreads();
  s = sm[0] + sm[1] + sm[2] + sm[3];
  s2 = sm[4] + sm[5] + sm[6] + sm[7];
  float mean = s * (1.f / HID);
  float var = s2 * (1.f / HID) - mean * mean;
  float rstd = rsqrtf(var + 1e-5f);
  float4 g4 = ((const float4*)gamma)[t];
  float4 b4 = ((const float4*)beta)[t];
  float4 ov;
  ov.x = (v.x - mean) * rstd * g4.x + b4.x;
  ov.y = (v.y - mean) * rstd * g4.y + b4.y;
  ov.z = (v.z - mean) * rstd * g4.z + b4.z;
  ov.w = (v.w - mean) * rstd * g4.w + b4.w;
  ((float4*)(out + (long)row * HID))[t] = ov;
}

extern "C" void kernel_launch(void* const* d_in, const int* in_sizes, int n_in,
                              void* d_out, int out_size, void* d_ws, size_t ws_size,
                              hipStream_t stream) {
  const float* x = (const float*)d_in[0];
  const float* Wq = (const float*)d_in[1];
  const float* bq = (const float*)d_in[2];
  const float* Wk = (const float*)d_in[3];
  const float* bk = (const float*)d_in[4];
  const float* Wv = (const float*)d_in[5];
  const float* bv = (const float*)d_in[6];
  const float* Wo = (const float*)d_in[7];
  const float* bo = (const float*)d_in[8];
  const float* gamma = (const float*)d_in[9];
  const float* beta = (const float*)d_in[10];

  char* ws = (char*)d_ws;
  f16* x_h = (f16*)(ws);                       //  8 MB (dead after QKV gemm)
  f16* Wqkv = (f16*)(ws + (8ll << 20));        //  6 MB
  f16* Wo_h = (f16*)(ws + (14ll << 20));       //  2 MB
  float* bqkv = (float*)(ws + (16ll << 20));   // 12 KB
  f16* qkv = (f16*)(ws + (17ll << 20));        // 24 MB [S,3072]
  f16* vt = (f16*)(ws + (41ll << 20));         //  8 MB blocked [16][64][64][64]
  f16* ctx = (f16*)(ws + (49ll << 20));        //  8 MB
  f16* part = (f16*)(ws + (57ll << 20));       // 32 MB [4][S][HID] (dead after combine)
  float* gbuf = (float*)(ws + (89ll << 20));   //  1 MB [4][S][NHEAD]
  float* res = (float*)(ws + (57ll << 20));    // 16 MB (overlays part[0..1], after combine)
  float2* tab = (float2*)(ws + (88ll << 20));  //  1 MB sincos (overlays part[3]; dead
                                               //  after rope, before attn writes part)
  const bool split = ws_size >= (90ull << 20);

  cvt_all<<<8192, 256, 0, stream>>>(x, Wq, Wk, Wv, Wo, x_h, Wqkv, Wo_h);
  rope_tab_bias<<<524, 256, 0, stream>>>(bq, bk, bv, bqkv, tab);

  gemm_f16<0><<<dim3(24, 32), 256, 0, stream>>>(x_h, Wqkv, bqkv, nullptr,
                                                qkv, vt, SEQ, 3 * HID, HID, 3 * HID);
  rope_kernel<<<SEQ * NHEAD * 4 / 256, 256, 0, stream>>>(qkv, tab);
  if (split) {
    flash_attn<4><<<dim3(SEQ / 128, NHEAD, 4), 256, 0, stream>>>(qkv, vt, part, gbuf);
    combine_kernel<4><<<SEQ * 128 / 256, 256, 0, stream>>>(part, gbuf, ctx);
  } else {
    flash_attn<1><<<dim3(SEQ / 128, NHEAD, 1), 256, 0, stream>>>(qkv, vt, ctx, nullptr);
  }
  gemm_f16<1><<<dim3(8, 32), 256, 0, stream>>>(ctx, Wo_h, bo, x,
                                               res, nullptr, SEQ, HID, HID, HID);
  ln_kernel<<<SEQ, 256, 0, stream>>>(res, gamma, beta, (float*)d_out);
}

// Round 19
// 174.997 us; speedup vs baseline: 3.2674x; 1.0027x over previous
//
#include <hip/hip_runtime.h>

typedef _Float16 f16;
typedef _Float16 f16x2 __attribute__((ext_vector_type(2)));
typedef _Float16 f16x4 __attribute__((ext_vector_type(4)));
typedef _Float16 f16x8 __attribute__((ext_vector_type(8)));
typedef float    f32x4 __attribute__((ext_vector_type(4)));
typedef float    f32x16 __attribute__((ext_vector_type(16)));

#define SEQ 4096
#define HID 1024
#define NHEAD 16

__device__ __forceinline__ void gload_lds16(const void* src, void* dst) {
  __builtin_amdgcn_global_load_lds(
      (__attribute__((address_space(1))) void*)(void*)src,
      (__attribute__((address_space(3))) void*)dst, 16, 0, 0);
}

__device__ __forceinline__ float fast_exp2(float x) {
#if __has_builtin(__builtin_amdgcn_exp2f)
  return __builtin_amdgcn_exp2f(x);
#else
  float r;
  asm("v_exp_f32 %0, %1" : "=v"(r) : "v"(x));
  return r;
#endif
}

__device__ __forceinline__ f16x2 cvt_pk_f16(float a, float b) {
  return __builtin_bit_cast(f16x2, __builtin_amdgcn_cvt_pkrtz(a, b));
}

__device__ __forceinline__ void perm32swap(unsigned& a, unsigned& b) {
  asm volatile("v_permlane32_swap_b32 %0, %1" : "+v"(a), "+v"(b));
}

union U32F16x2 { unsigned u; f16x2 h; };
union PFU { unsigned u[4]; f16x8 v; };

// period-16 LDS column swizzle (2-way residual = free per m136)
#define SWZ(row) ((((row) & 7) ^ (((row) & 8) >> 1)))

// ---------------- conversions (x + all 4 weights, one launch) ----------------
__global__ void cvt_all(const float* __restrict__ x,
                        const float* __restrict__ Wq, const float* __restrict__ Wk,
                        const float* __restrict__ Wv, const float* __restrict__ Wo,
                        f16* __restrict__ x_h, f16* __restrict__ Wqkv,
                        f16* __restrict__ Wo_h) {
  int bx = blockIdx.x;
  const float* s;
  f16* o;
  long i;
  if (bx < 4096) {
    s = x; o = x_h;
    i = (long)bx * 256 + threadIdx.x;
  } else {
    int wsel = (bx - 4096) >> 10;
    i = (long)((bx - 4096) & 1023) * 256 + threadIdx.x;
    s = wsel == 0 ? Wq : wsel == 1 ? Wk : wsel == 2 ? Wv : Wo;
    o = wsel < 3 ? Wqkv + (long)wsel * HID * HID : Wo_h;
  }
  float4 v = ((const float4*)s)[i];
  f16x4 h;
  h[0] = (f16)v.x; h[1] = (f16)v.y; h[2] = (f16)v.z; h[3] = (f16)v.w;
  *(f16x4*)(o + i * 4) = h;
}

// sincos table for RoPE (shared across the 16 heads) + bias pack, one launch
__global__ void rope_tab_bias(const float* __restrict__ bq, const float* __restrict__ bk,
                              const float* __restrict__ bv, float* __restrict__ bqkv,
                              float2* __restrict__ tab) {
  int bx = blockIdx.x;
  if (bx < 512) {
    int idx = bx * 256 + threadIdx.x;  // [0, SEQ*32)
    int s = idx >> 5, j = idx & 31;
    float freq = __expf(-(float)j * 0.2878231366242557f);  // 10000^(-j/32)
    float sn, cs;
    sincosf((float)s * freq, &sn, &cs);
    tab[idx] = make_float2(cs, sn);
  } else {
    int i = (bx - 512) * 256 + threadIdx.x;
    if (i < 3 * HID) {
      float v = (i < HID) ? bq[i] : (i < 2 * HID ? bk[i - HID] : bv[i - 2 * HID]);
      bqkv[i] = v;
    }
  }
}

// ---------------- GEMM: C = A @ B^T (+bias [+resid]) ----------------
// MODE 0: QKV projection, plain bias epilogue. V cols stored to out2 in blocked
//         layout [head][kvblk=S/64][d64][kv64].
// MODE 1: out proj with split-K (SK partitions over blockIdx.z): each partition
//         writes an f32 partial to out + z*SEQ*ldo; bias+resid folded into z=0.
//         256 blocks = 1 block/CU was the bottleneck; SK=2 -> 2 blocks/CU.
template <int MODE, int SK>
__global__ __launch_bounds__(256) void gemm_f16(
    const f16* __restrict__ A, const f16* __restrict__ B,
    const float* __restrict__ bias, const float* __restrict__ resid,
    void* __restrict__ out, void* __restrict__ out2,
    int M, int N, int K, int ldo) {
  __shared__ alignas(16) f16 As[128 * 64];
  __shared__ alignas(16) f16 Bs[128 * 64];
  const int tid = threadIdx.x;
  const int lane = tid & 63;
  const int w = tid >> 6;
  const int wr = w >> 1, wc = w & 1;
  const int l15 = lane & 15, g = lane >> 4;
  // XCD-aware bijective swizzle per z-slice (nwg % 8 == 0 for both call sites)
  const int nwg = gridDim.x * gridDim.y;
  const int flat = blockIdx.y * gridDim.x + blockIdx.x;
  const int swz = (flat & 7) * (nwg >> 3) + (flat >> 3);
  const int m0 = (swz / gridDim.x) * 128;
  const int n0 = (swz % gridDim.x) * 128;
  const int z = (SK > 1) ? blockIdx.z : 0;

  f32x4 acc[4][4] = {};
  const int nkt = (K >> 6) / SK;
  const int kt0 = z * nkt;
  for (int kt = kt0; kt < kt0 + nkt; ++kt) {
#pragma unroll
    for (int i = 0; i < 4; ++i) {
      int c = i * 256 + w * 64 + lane;
      int row = c >> 3, c8 = c & 7;
      int so = ((c8 * 8) ^ ((row & 7) << 3)) + kt * 64;
      gload_lds16(A + (long)(m0 + row) * K + so, As + (i * 256 + w * 64) * 8);
      gload_lds16(B + (long)(n0 + row) * K + so, Bs + (i * 256 + w * 64) * 8);
    }
    __syncthreads();
#pragma unroll
    for (int kk = 0; kk < 2; ++kk) {
      f16x8 af[4], bf[4];
#pragma unroll
      for (int t = 0; t < 4; ++t) {
        int ra = wr * 64 + t * 16 + l15;
        af[t] = *(const f16x8*)(As + ra * 64 + ((kk * 32 + g * 8) ^ ((ra & 7) << 3)));
        int rb = wc * 64 + t * 16 + l15;
        bf[t] = *(const f16x8*)(Bs + rb * 64 + ((kk * 32 + g * 8) ^ ((rb & 7) << 3)));
      }
      __builtin_amdgcn_s_setprio(1);
#pragma unroll
      for (int mi = 0; mi < 4; ++mi)
#pragma unroll
        for (int ni = 0; ni < 4; ++ni)
          acc[mi][ni] = __builtin_amdgcn_mfma_f32_16x16x32_f16(af[mi], bf[ni], acc[mi][ni], 0, 0, 0);
      __builtin_amdgcn_s_setprio(0);
    }
    __syncthreads();
  }
#pragma unroll
  for (int mi = 0; mi < 4; ++mi) {
    int row = m0 + wr * 64 + mi * 16 + g * 4;
#pragma unroll
    for (int ni = 0; ni < 4; ++ni) {
      int col = n0 + wc * 64 + ni * 16 + l15;
      if (MODE == 0) {
        float bv = bias[col];
        if (col < 2 * HID) {
          f16* o = (f16*)out;
#pragma unroll
          for (int r = 0; r < 4; ++r)
            o[(long)(row + r) * ldo + col] = (f16)(acc[mi][ni][r] + bv);
        } else {
          // V block: blocked-transposed store [head][kvblk][d64][kv64]
          f16* vtp = (f16*)out2;
          f16x4 pk;
#pragma unroll
          for (int r = 0; r < 4; ++r) pk[r] = (f16)(acc[mi][ni][r] + bv);
          int cv = col - 2 * HID;          // 0..1023
          int headv = cv >> 6, dv = cv & 63;
          *(f16x4*)(vtp + (long)headv * SEQ * 64 + (long)(row >> 6) * 4096 +
                    dv * 64 + (row & 63)) = pk;
        }
      } else {
        float* o = (float*)out + (long)z * SEQ * ldo;
        if (z == 0) {
          float bv = bias[col];
#pragma unroll
          for (int r = 0; r < 4; ++r)
            o[(long)(row + r) * ldo + col] =
                acc[mi][ni][r] + bv + resid[(long)(row + r) * HID + col];
        } else {
#pragma unroll
          for (int r = 0; r < 4; ++r)
            o[(long)(row + r) * ldo + col] = acc[mi][ni][r];
        }
      }
    }
  }
}

// ---------------- RoPE in place on Q and K halves of qkv (table-driven) --------
// Q additionally pre-scaled by 0.125*log2(e) (rotation and scale commute).
__global__ void rope_kernel(f16* __restrict__ qkv, const float2* __restrict__ tab) {
  int idx = blockIdx.x * 256 + threadIdx.x;  // [0, SEQ*16*4)
  int u = idx & 3, h = (idx >> 2) & 15, s = idx >> 6;
  const float2* tp = tab + s * 32 + u * 8;
  const float qsc = 0.18033688f;
  f16* qp = qkv + (long)s * 3072 + h * 64 + u * 8;
  f16x8 qlo = *(const f16x8*)qp;
  f16x8 qhi = *(const f16x8*)(qp + 32);
  f16x8 klo = *(const f16x8*)(qp + HID);
  f16x8 khi = *(const f16x8*)(qp + HID + 32);
  f16x8 nql, nqh, nkl, nkh;
#pragma unroll
  for (int i = 0; i < 8; ++i) {
    float cs = tp[i].x, sn = tp[i].y;
    nql[i] = (f16)(((float)qlo[i] * cs - (float)qhi[i] * sn) * qsc);
    nqh[i] = (f16)(((float)qhi[i] * cs + (float)qlo[i] * sn) * qsc);
    nkl[i] = (f16)((float)klo[i] * cs - (float)khi[i] * sn);
    nkh[i] = (f16)((float)khi[i] * cs + (float)klo[i] * sn);
  }
  *(f16x8*)qp = nql;
  *(f16x8*)(qp + 32) = nqh;
  *(f16x8*)(qp + HID) = nkl;
  *(f16x8*)(qp + HID + 32) = nkh;
}

// ---------------- flash attention (swapped 32x32, no-max softmax, KV-split NS) ----
// XCD-clustered; V blocked [head][kvblk][d64][kv64]; f32-sum softmax (R13-best).
// grid (32, 16, NS), 256 threads = 4 waves; wave owns 32 q rows (q=lane&31).
// Q arrives pre-scaled by 0.125*log2(e) (folded into rope).
// launch_bounds(256,4) — unified VGPR+AGPR file caps this state at 4 waves/SIMD;
// (256,5)/(512,8) both force spill storms (R14/R17).
template <int NS>
__global__ __launch_bounds__(256, 4) void flash_attn(
    const f16* __restrict__ qkv, const f16* __restrict__ vt,
    f16* __restrict__ ctx_or_part, float* __restrict__ gbuf) {
  __shared__ alignas(16) f16 Ks[2][64 * 64];
  __shared__ alignas(16) f16 Vs[2][64 * 64];  // [d][kv]
  const int tid = threadIdx.x, lane = tid & 63, w = tid >> 6;
  const int l31 = lane & 31, hi = lane >> 5;
  // XCD remap: hw xcd = flat%8; group g=(head,z) constant per XCD
  const int flat = blockIdx.x + ((blockIdx.y + (blockIdx.z << 4)) << 5);
  const int seq = flat >> 3;
  const int g = (flat & 7) + ((seq >> 5) << 3);
  const int head = g & 15;
  const int z = (NS > 1) ? (g >> 4) : 0;
  const int q0 = (seq & 31) * 128 + w * 32;
  const int span = SEQ / NS;
  const int kvbase = z * span;

  // Q fragments: q-row = l31, d = dt*16 + hi*8 + i (already scaled).
  f16x8 qf[4];
  {
    const f16* qp = qkv + (long)(q0 + l31) * 3072 + head * 64 + hi * 8;
#pragma unroll
    for (int dt = 0; dt < 4; ++dt)
      qf[dt] = *(const f16x8*)(qp + dt * 16);
  }

  const f16* kbase = qkv + HID + head * 64;
  const f16* vbase = vt + (long)head * SEQ * 64;

  float l_r = 0.f;
  f32x16 oacc[2] = {};  // O^T[d][q=l31]; d = dsub*32 + (r&3)+8*(r>>2)+4*hi

#define STAGE(buf, kv0)                                                            \
  {                                                                                \
    _Pragma("unroll") for (int i = 0; i < 2; ++i) {                                \
      int c = i * 256 + w * 64 + lane;                                             \
      int row = c >> 3, c8 = c & 7;                                                \
      int so = (c8 ^ SWZ(row)) * 8;                                                \
      gload_lds16(kbase + (long)((kv0) + row) * 3072 + so,                         \
                  &Ks[buf][(i * 256 + w * 64) * 8]);                               \
      gload_lds16(vbase + (long)((kv0) >> 6) * 4096 + row * 64 + so,               \
                  &Vs[buf][(i * 256 + w * 64) * 8]);                               \
    }                                                                              \
  }

  STAGE(0, kvbase);
  __syncthreads();

  for (int it = 0; it < span / 64; ++it) {
    const int cur = it & 1;
    if (it + 1 < span / 64) STAGE(cur ^ 1, kvbase + it * 64 + 64);

    // S^T[kv][q] = K · Q^T  (dt-major: the two sacc chains interleave, dep dist 2)
    f32x16 sacc[2] = {};
    __builtin_amdgcn_s_setprio(1);
#pragma unroll
    for (int dt = 0; dt < 4; ++dt) {
#pragma unroll
      for (int sub = 0; sub < 2; ++sub) {
        int row = sub * 32 + l31;
        f16x8 kf = *(const f16x8*)(&Ks[cur][row * 64 +
                                            ((dt * 16 + hi * 8) ^ (SWZ(row) << 3))]);
        sacc[sub] = __builtin_amdgcn_mfma_f32_32x32x16_f16(kf, qf[dt], sacc[sub], 0, 0, 0);
      }
    }
    __builtin_amdgcn_s_setprio(0);

    // ---- softmax numerator, no max-shift: P = exp2(s) directly ----
    f16x2 h[16];
    float sm0 = 0.f, sm1 = 0.f, sm2 = 0.f, sm3 = 0.f;
#pragma unroll
    for (int sub = 0; sub < 2; ++sub)
#pragma unroll
      for (int u = 0; u < 8; ++u) {
        float p0 = fast_exp2(sacc[sub][2 * u]);
        float p1 = fast_exp2(sacc[sub][2 * u + 1]);
        h[sub * 8 + u] = cvt_pk_f16(p0, p1);
        if (sub == 0) { sm0 += p0; sm1 += p1; }
        else          { sm2 += p0; sm3 += p1; }
      }
    float sum = (sm0 + sm1) + (sm2 + sm3);
    sum += __shfl_xor(sum, 32);
    l_r += sum;

    // T12: permlane32_swap so P fragment kv-map becomes kv = t*16 + 8*hi + j
    f16x8 pf[4];
#pragma unroll
    for (int t = 0; t < 4; ++t) {
      int base = (t >> 1) * 8 + (t & 1) * 4;
      U32F16x2 c0, c1, c2, c3;
      c0.h = h[base + 0]; c1.h = h[base + 1];
      c2.h = h[base + 2]; c3.h = h[base + 3];
      perm32swap(c0.u, c2.u);
      perm32swap(c1.u, c3.u);
      PFU p;
      p.u[0] = c0.u; p.u[1] = c1.u; p.u[2] = c2.u; p.u[3] = c3.u;
      pf[t] = p.v;
    }

    // O^T += V^T · P — contiguous b128 V reads (kv = t*16 + 8*hi + 0..7)
    __builtin_amdgcn_s_setprio(1);
#pragma unroll
    for (int dsub = 0; dsub < 2; ++dsub) {
      int row = dsub * 32 + l31;
      const f16* vrow = &Vs[cur][row * 64];
      int sw = SWZ(row) << 3;
#pragma unroll
      for (int t = 0; t < 4; ++t) {
        f16x8 af = *(const f16x8*)(vrow + ((t * 16 + hi * 8) ^ sw));
        oacc[dsub] = __builtin_amdgcn_mfma_f32_32x32x16_f16(af, pf[t], oacc[dsub], 0, 0, 0);
      }
    }
    __builtin_amdgcn_s_setprio(0);
    __syncthreads();
  }

  // epilogue: normalize, transpose O^T -> O via LDS (rotation swizzle, conflict-free)
  f16* ob = &Ks[0][0] + w * 2048;  // wave-local 32x64 tile
  float linv = 1.0f / l_r;
#pragma unroll
  for (int dsub = 0; dsub < 2; ++dsub)
#pragma unroll
    for (int a = 0; a < 8; ++a) {
      int rr = a * 2;
      int d = dsub * 32 + (rr & 3) + 8 * (rr >> 2) + 4 * hi;  // d, d+1 pair
      f16x2 pk;
      pk[0] = (f16)(oacc[dsub][rr] * linv);
      pk[1] = (f16)(oacc[dsub][rr + 1] * linv);
      *(f16x2*)(ob + l31 * 64 + ((d + 2 * l31) & 63)) = pk;
    }
  if (NS > 1 && hi == 0)
    gbuf[(long)z * SEQ * NHEAD + (long)(q0 + l31) * NHEAD + head] = __log2f(l_r);
  {
    f16* obase = (NS > 1) ? ctx_or_part + (long)z * SEQ * HID : ctx_or_part;
    int dblk = lane & 7, r0 = lane >> 3;
#pragma unroll
    for (int j = 0; j < 4; ++j) {
      int q = r0 + j * 8;
      f16x2 vv[4];
#pragma unroll
      for (int i = 0; i < 4; ++i)
        vv[i] = *(const f16x2*)(ob + q * 64 + ((dblk * 8 + 2 * i + 2 * q) & 63));
      f16x8 o8;
#pragma unroll
      for (int i = 0; i < 4; ++i) { o8[2 * i] = vv[i][0]; o8[2 * i + 1] = vv[i][1]; }
      *(f16x8*)(obase + (long)(q0 + q) * HID + head * 64 + dblk * 8) = o8;
    }
  }
#undef STAGE
}

// combine NS normalized partials: w_z = 2^(g_z - G) softmax weights
template <int NS>
__global__ __launch_bounds__(256) void combine_kernel(
    const f16* __restrict__ part, const float* __restrict__ g,
    f16* __restrict__ ctx) {
  long idx = (long)blockIdx.x * 256 + threadIdx.x;  // [0, SEQ*128)
  int q = (int)(idx >> 7), c = (int)(idx & 127);
  int head = c >> 3;
  float gv[NS];
  float G = -1e30f;
#pragma unroll
  for (int zz = 0; zz < NS; ++zz) {
    gv[zz] = g[(long)zz * SEQ * NHEAD + (long)q * NHEAD + head];
    G = fmaxf(G, gv[zz]);
  }
  float wz[NS], tot = 0.f;
#pragma unroll
  for (int zz = 0; zz < NS; ++zz) { wz[zz] = fast_exp2(gv[zz] - G); tot += wz[zz]; }
  float inv = 1.f / tot;
  float acc[8] = {};
#pragma unroll
  for (int zz = 0; zz < NS; ++zz) {
    f16x8 a = *(const f16x8*)(part + (long)zz * SEQ * HID + (long)q * HID + c * 8);
    float wzz = wz[zz] * inv;
#pragma unroll
    for (int j = 0; j < 8; ++j) acc[j] += (float)a[j] * wzz;
  }
  f16x8 o;
#pragma unroll
  for (int j = 0; j < 8; ++j) o[j] = (f16)acc[j];
  *(f16x8*)(ctx + (long)q * HID + c * 8) = o;
}

// ---------------- LayerNorm over the sum of two split-K partials ----------------
__global__ __launch_bounds__(256) void ln_kernel(
    const float* __restrict__ res0, const float* __restrict__ res1,
    const float* __restrict__ gamma, const float* __restrict__ beta,
    float* __restrict__ out) {
  int row = blockIdx.x;
  int t = threadIdx.x;
  float4 v0 = ((const float4*)(res0 + (long)row * HID))[t];
  float4 v1 = ((const float4*)(res1 + (long)row * HID))[t];
  float4 v;
  v.x = v0.x + v1.x; v.y = v0.y + v1.y; v.z = v0.z + v1.z; v.w = v0.w + v1.w;
  float s = v.x + v.y + v.z + v.w;
  float s2 = v.x * v.x + v.y * v.y + v.z * v.z + v.w * v.w;
#pragma unroll
  for (int off = 1; off < 64; off <<= 1) {
    s += __shfl_xor(s, off);
    s2 += __shfl_xor(s2, off);
  }
  __shared__ float sm[8];
  int w = t >> 6, lane = t & 63;
  if (lane == 0) { sm[w] = s; sm[4 + w] = s2; }
  __syncthreads();
  s = sm[0] + sm[1] + sm[2] + sm[3];
  s2 = sm[4] + sm[5] + sm[6] + sm[7];
  float mean = s * (1.f / HID);
  float var = s2 * (1.f / HID) - mean * mean;
  float rstd = rsqrtf(var + 1e-5f);
  float4 g4 = ((const float4*)gamma)[t];
  float4 b4 = ((const float4*)beta)[t];
  float4 ov;
  ov.x = (v.x - mean) * rstd * g4.x + b4.x;
  ov.y = (v.y - mean) * rstd * g4.y + b4.y;
  ov.z = (v.z - mean) * rstd * g4.z + b4.z;
  ov.w = (v.w - mean) * rstd * g4.w + b4.w;
  ((float4*)(out + (long)row * HID))[t] = ov;
}

extern "C" void kernel_launch(void* const* d_in, const int* in_sizes, int n_in,
                              void* d_out, int out_size, void* d_ws, size_t ws_size,
                              hipStream_t stream) {
  const float* x = (const float*)d_in[0];
  const float* Wq = (const float*)d_in[1];
  const float* bq = (const float*)d_in[2];
  const float* Wk = (const float*)d_in[3];
  const float* bk = (const float*)d_in[4];
  const float* Wv = (const float*)d_in[5];
  const float* bv = (const float*)d_in[6];
  const float* Wo = (const float*)d_in[7];
  const float* bo = (const float*)d_in[8];
  const float* gamma = (const float*)d_in[9];
  const float* beta = (const float*)d_in[10];

  char* ws = (char*)d_ws;
  f16* x_h = (f16*)(ws);                       //  8 MB (dead after QKV gemm)
  f16* Wqkv = (f16*)(ws + (8ll << 20));        //  6 MB
  f16* Wo_h = (f16*)(ws + (14ll << 20));       //  2 MB
  float* bqkv = (float*)(ws + (16ll << 20));   // 12 KB
  f16* qkv = (f16*)(ws + (17ll << 20));        // 24 MB [S,3072]
  f16* vt = (f16*)(ws + (41ll << 20));         //  8 MB blocked [16][64][64][64]
  f16* ctx = (f16*)(ws + (49ll << 20));        //  8 MB
  f16* part = (f16*)(ws + (57ll << 20));       // 32 MB [4][S][HID] (dead after combine)
  float* gbuf = (float*)(ws + (89ll << 20));   //  1 MB [4][S][NHEAD]
  float* res = (float*)(ws + (57ll << 20));    // 2x16 MB split-K partials (overlay part,
                                               //  written after combine)
  float2* tab = (float2*)(ws + (88ll << 20));  //  1 MB sincos (overlays part[3]; dead
                                               //  after rope, before attn writes part)
  const bool split = ws_size >= (90ull << 20);

  cvt_all<<<8192, 256, 0, stream>>>(x, Wq, Wk, Wv, Wo, x_h, Wqkv, Wo_h);
  rope_tab_bias<<<524, 256, 0, stream>>>(bq, bk, bv, bqkv, tab);

  gemm_f16<0, 1><<<dim3(24, 32), 256, 0, stream>>>(x_h, Wqkv, bqkv, nullptr,
                                                   qkv, vt, SEQ, 3 * HID, HID, 3 * HID);
  rope_kernel<<<SEQ * NHEAD * 4 / 256, 256, 0, stream>>>(qkv, tab);
  if (split) {
    flash_attn<4><<<dim3(SEQ / 128, NHEAD, 4), 256, 0, stream>>>(qkv, vt, part, gbuf);
    combine_kernel<4><<<SEQ * 128 / 256, 256, 0, stream>>>(part, gbuf, ctx);
    gemm_f16<1, 2><<<dim3(8, 32, 2), 256, 0, stream>>>(ctx, Wo_h, bo, x,
                                                       res, nullptr, SEQ, HID, HID, HID);
    ln_kernel<<<SEQ, 256, 0, stream>>>(res, res + (long)SEQ * HID, gamma, beta,
                                       (float*)d_out);
  } else {
    flash_attn<1><<<dim3(SEQ / 128, NHEAD, 1), 256, 0, stream>>>(qkv, vt, ctx, nullptr);
    gemm_f16<1, 2><<<dim3(8, 32, 2), 256, 0, stream>>>(ctx, Wo_h, bo, x,
                                                       res, nullptr, SEQ, HID, HID, HID);
    ln_kernel<<<SEQ, 256, 0, stream>>>(res, res + (long)SEQ * HID, gamma, beta,
                                       (float*)d_out);
  }
}